// Round 4
// baseline (180.110 us; speedup 1.0000x reference)
//
#include <hip/hip_runtime.h>
#include <stdint.h>

// TopoAELoss: two dense-graph MSTs (Boruvka) + sum of squared weight
// differences over both MST edge sets.
//
// R14 change: explicit MLP. R13 counters showed cold_k VGPR_Count=12 —
// the compiler kept the scan rolled (load->waitcnt->consume per float4),
// per-lane MLP ~1, so cold_k sat at 44us / 2.9 TB/s consumed with VALU
// 22% + HBM 20% (latency-bound, both pipes idle). Same structure made the
// heavy warm round (half-matrix rescan after a big merge) 41.7us at 1.45
// TB/s. Fix: hoist all 16 float4 row loads into a statically-indexed
// register array (issues 16 outstanding loads/lane), reduce over 4
// independent u64 accumulators (serial min-chain 64 -> 16 links). Applied
// to cold_k and warm_k's dead-lane rescan. ~90 VGPR -> still 5-6
// waves/SIMD. NOTE: the R11 "shuffle-latency" theory was WRONG — R13
// removed all per-chunk shuffles and cold_k did not move; MLP is the
// lever.
//
// R13 lesson: ROUNDS must be 12 = ceil(log2(4096)) — the harness
// re-poisons inputs for the post-timing check; 10 rounds failed on a
// fresh instance. done[]-gated rounds cost only launch overhead. NEVER
// lower below 12.
// R12 geometry kept: chunk l = interleaved column set {k*256+l*4+q}; lane
// l reads float4 index k*64+lane — fully-coalesced 1KB wave loads, per-
// chunk min is lane-private, ONE wave_min64 per row. cand[] = 64/row.
// R11 lesson: lane-owns-CONTIGUOUS-chunk destroys coalescing (FETCH
// 64MB->359MB). Chunks must be interleaved.
// R10 lesson: do NOT fuse contraction into the scan kernel.
//
// Layout of d_ws:
//   best : 2*4096 u64  @ 0       (65536 B)
//   comp : 2*4096 i32  @ 65536   (32768 B)
//   done : 2     i32   @ 98304   (8 B)
//   cand : 2*4096*64 u64 @ 98312 (4 MiB)   per-(row,lane-chunk) best edge

#define NPTS 4096
#define NCHUNK 64                   // interleaved chunks per row, 1 per lane
#define NBLK 1024                   // blocks per problem (4 rows each)
#define ROUNDS 12                   // ceil(log2(4096)) — sufficient for ANY
                                    // input. NEVER lower below 12.

typedef unsigned long long u64;
typedef float nfloat4 __attribute__((ext_vector_type(4)));

__device__ __forceinline__ u64 umin64(u64 a, u64 b) { return a < b ? a : b; }

// [ w_bits:32 | min(i,j):12 | max(i,j):12 ] — strict total order, symmetric.
__device__ __forceinline__ u64 pack_edge(float w, int i, int j) {
    unsigned wb = __float_as_uint(w);
    int u = i < j ? i : j;
    int v = i < j ? j : i;
    return ((u64)wb << 24) | ((u64)(unsigned)u << 12) | (u64)(unsigned)v;
}

__device__ __forceinline__ u64 wave_min64(u64 v) {
    #pragma unroll
    for (int off = 32; off; off >>= 1)
        v = umin64(v, __shfl_down(v, (unsigned)off, 64));
    return v;   // valid in lane 0
}

// Cold scan (round 1, comp = identity): 1 row per wave; lane l owns the
// interleaved chunk {k*256 + l*4 + q}. All 16 float4 loads hoisted into
// registers (MLP 16), then reduced via 4 independent accumulators.
// Lane-private min -> cand[row][l] (coalesced 512B store); one wave_min64
// -> best[i]. One thread also zeroes done[] and out[].
__global__ __launch_bounds__(256) void cold_k(
    const float* __restrict__ D1, const float* __restrict__ D2,
    u64* __restrict__ best, u64* __restrict__ cand,
    int* __restrict__ done, float* __restrict__ out) {
    if (blockIdx.x == 0 && threadIdx.x == 0) {
        done[0] = 0; done[1] = 0; out[0] = 0.f;
    }
    int pb = blockIdx.x >> 10;
    int rb = blockIdx.x & (NBLK - 1);
    const float* __restrict__ D = pb ? D2 : D1;
    u64* __restrict__ bst = best + pb * NPTS;
    u64* __restrict__ cnd = cand + (size_t)pb * NPTS * NCHUNK;

    int wave = threadIdx.x >> 6, lane = threadIdx.x & 63;
    int i = rb * 4 + wave;
    const nfloat4* __restrict__ row = (const nfloat4*)(D + (size_t)i * NPTS);

    nfloat4 w[16];
    #pragma unroll
    for (int k = 0; k < 16; ++k) w[k] = row[k * 64 + lane];   // 16 in flight

    u64 acc[4] = { ~0ull, ~0ull, ~0ull, ~0ull };
    #pragma unroll
    for (int k = 0; k < 16; ++k) {
        int j0 = k * 256 + lane * 4;
        #pragma unroll
        for (int q = 0; q < 4; ++q)
            if (j0 + q != i)
                acc[k & 3] = umin64(acc[k & 3], pack_edge(w[k][q], i, j0 + q));
    }
    u64 m = umin64(umin64(acc[0], acc[1]), umin64(acc[2], acc[3]));

    cnd[i * NCHUNK + lane] = m;          // coalesced 64-lane store
    u64 bv = wave_min64(m);
    if (lane == 0) bst[i] = bv;          // comp identity: row-private, no atomic
}

// Warm scan: 1 row per wave. Each lane validates its own candidate against
// current comp; dead lanes privately rescan their interleaved chunk with
// hoisted loads (MLP 16). One wave_min64 per row; atomicMin per row.
__global__ __launch_bounds__(256) void warm_k(
    const float* __restrict__ D1, const float* __restrict__ D2,
    u64* __restrict__ best, const int* __restrict__ comp,
    const int* __restrict__ done, u64* __restrict__ cand) {
    int pb = blockIdx.x >> 10;
    if (done[pb]) return;
    int rb = blockIdx.x & (NBLK - 1);
    const float* __restrict__ D = pb ? D2 : D1;
    const int* __restrict__ cmpg = comp + pb * NPTS;
    u64* __restrict__ bst = best + pb * NPTS;
    u64* __restrict__ cnd = cand + (size_t)pb * NPTS * NCHUNK;

    int wave = threadIdx.x >> 6, lane = threadIdx.x & 63;
    int i = rb * 4 + wave;
    int ci = cmpg[i];

    u64 live = ~0ull;
    u64 c = cnd[i * NCHUNK + lane];      // coalesced 64-lane load
    if (c != ~0ull) {                    // ~0ull: chunk permanently all-internal
        int u = (int)((c >> 12) & 0xFFF), v = (int)(c & 0xFFF);
        int j = (u == i) ? v : u;
        if (cmpg[j] != ci) {
            live = c;                    // far endpoint still external -> exact
        } else {
            // absorbed -> lane-private rescan of interleaved chunk.
            const nfloat4* __restrict__ row =
                (const nfloat4*)(D + (size_t)i * NPTS);
            nfloat4 w[16];
            #pragma unroll
            for (int k = 0; k < 16; ++k) w[k] = row[k * 64 + lane];
            u64 acc[4] = { ~0ull, ~0ull, ~0ull, ~0ull };
            #pragma unroll
            for (int k = 0; k < 16; ++k) {
                int j0 = k * 256 + lane * 4;
                int4 cj = *(const int4*)&cmpg[j0];   // L1-hot (16 KB array)
                // diagonal j==i auto-excluded: cmpg[i] == ci
                if (cj.x != ci) acc[k & 3] = umin64(acc[k & 3], pack_edge(w[k].x, i, j0));
                if (cj.y != ci) acc[k & 3] = umin64(acc[k & 3], pack_edge(w[k].y, i, j0 + 1));
                if (cj.z != ci) acc[k & 3] = umin64(acc[k & 3], pack_edge(w[k].z, i, j0 + 2));
                if (cj.w != ci) acc[k & 3] = umin64(acc[k & 3], pack_edge(w[k].w, i, j0 + 3));
            }
            u64 m = umin64(umin64(acc[0], acc[1]), umin64(acc[2], acc[3]));
            cnd[i * NCHUNK + lane] = m;
            live = m;
        }
    }
    u64 rmin = wave_min64(live);
    // pre-check: stale plain read >= current (best monotone decreasing) -> safe
    if (lane == 0 && rmin != ~0ull && rmin < bst[ci]) atomicMin(&bst[ci], rmin);
}

// One block (1024 threads) per problem: hook, break 2-cycles, accumulate
// deduped edge losses, pointer-jump, relabel, reset best, set done, add loss.
// identity=1 for round 1 (comp[x]==x implicit -> comp needs no init kernel).
__global__ __launch_bounds__(1024) void contract_k(
    const float* __restrict__ D1, const float* __restrict__ D2,
    u64* __restrict__ best, int* __restrict__ comp,
    int* __restrict__ done, float* __restrict__ out, int identity) {
    int pb = blockIdx.x;
    if (!identity && done[pb]) return;
    u64* __restrict__ bst = best + pb * NPTS;
    int* __restrict__ cmp = comp + pb * NPTS;

    __shared__ int link_s[NPTS];
    __shared__ float red_s[16];
    __shared__ int flag_s;
    int t = threadIdx.x;
    float loss = 0.f;

    int eu[4], ev[4], nl[4];
    bool act[4];

    for (int q = 0; q < 4; ++q) {
        int c = t + q * 1024;
        u64 b = bst[c];
        bool a = (b != ~0ull);
        act[q] = a;
        int u = (int)((b >> 12) & 0xFFF), v = (int)(b & 0xFFF);
        eu[q] = u; ev[q] = v;
        int l = c;
        if (a) {
            if (identity) l = (u == c) ? v : u;
            else { int cu = cmp[u]; l = (cu == c) ? cmp[v] : cu; }
        }
        link_s[c] = l;
    }
    __syncthreads();

    for (int q = 0; q < 4; ++q) {
        int c = t + q * 1024;
        int l = link_s[c];
        bool is2 = (l != c) && (link_s[l] == c);
        if (act[q] && !(is2 && c > l)) {
            size_t off = (size_t)eu[q] * NPTS + ev[q];
            float d = D1[off] - D2[off];
            loss += d * d;
        }
        nl[q] = (is2 && c < l) ? c : l;
    }
    __syncthreads();
    for (int q = 0; q < 4; ++q) link_s[t + q * 1024] = nl[q];
    __syncthreads();

    for (int it = 0; it < 13; ++it) {
        if (t == 0) flag_s = 0;
        __syncthreads();
        bool ch = false;
        for (int q = 0; q < 4; ++q) {
            int c = t + q * 1024;
            int l = link_s[c];
            int ll = link_s[l];
            nl[q] = ll;
            ch |= (ll != l);
        }
        if (ch) flag_s = 1;
        __syncthreads();
        for (int q = 0; q < 4; ++q) link_s[t + q * 1024] = nl[q];
        __syncthreads();
        if (!flag_s) break;
    }

    int c0 = identity ? 0 : cmp[0];
    __syncthreads();
    int root0 = link_s[c0];
    int same = 1;
    for (int q = 0; q < 4; ++q) {
        int v = t + q * 1024;
        int oc = identity ? v : cmp[v];
        int r = link_s[oc];
        cmp[v] = r;
        same &= (r == root0);
        bst[v] = ~0ull;
    }
    int all = __syncthreads_and(same);
    if (all && t == 0) done[pb] = 1;

    #pragma unroll
    for (int off = 32; off; off >>= 1) loss += __shfl_down(loss, (unsigned)off, 64);
    int wave = t >> 6, lane = t & 63;
    if (lane == 0) red_s[wave] = loss;
    __syncthreads();
    if (t == 0) {
        float s = 0.f;
        for (int wv = 0; wv < 16; ++wv) s += red_s[wv];
        atomicAdd(out, s);
    }
}

extern "C" void kernel_launch(void* const* d_in, const int* in_sizes, int n_in,
                              void* d_out, int out_size, void* d_ws, size_t ws_size,
                              hipStream_t stream) {
    const float* D1 = (const float*)d_in[0];   // input_distances  (4096x4096 f32)
    const float* D2 = (const float*)d_in[1];   // latent_distances (4096x4096 f32)
    float* out = (float*)d_out;

    char* ws = (char*)d_ws;
    u64* best = (u64*)ws;                          // 65536 B
    int* comp = (int*)(ws + 65536);                // 32768 B
    int* done = (int*)(ws + 65536 + 32768);        // 8 B
    u64* cand = (u64*)(ws + 98312);                // 4 MiB

    cold_k<<<2 * NBLK, 256, 0, stream>>>(D1, D2, best, cand, done, out);
    contract_k<<<2, 1024, 0, stream>>>(D1, D2, best, comp, done, out, 1);
    for (int r = 1; r < ROUNDS; ++r) {
        warm_k<<<2 * NBLK, 256, 0, stream>>>(D1, D2, best, comp, done, cand);
        contract_k<<<2, 1024, 0, stream>>>(D1, D2, best, comp, done, out, 0);
    }
}

// Round 5
// 178.887 us; speedup vs baseline: 1.0068x; 1.0068x over previous
//
#include <hip/hip_runtime.h>
#include <stdint.h>

// TopoAELoss: two dense-graph MSTs (Boruvka) + sum of squared weight
// differences over both MST edge sets.
//
// R15 change: persistent 2-row software-pipelined cold_k. Evidence chain:
// R13 (removed all shuffle chains: no change) + R14 (hoisted burst-16
// loads: no change, slightly worse) => cold_k is pinned at ~3 TB/s
// consumption independent of in-wave ILP. The m13 copy kernel reaches
// 6.3 TB/s with the SAME per-instruction pattern but CONTINUOUS loading
// (grid-stride, next iteration's loads in flight during current
// processing). cold_k waves were burst-then-die: 16 loads -> drain ->
// ~900cy compute with nothing in flight -> exit. Fix: each wave owns two
// rows (i0, i0+2048), row split into two 8-load stages, explicit P/Q
// ping-pong (static indexing only): issue S0,S1(row0); compute S0 while
// S2(row1) issues; compute S1 while S3 issues; finish row0; compute
// S2,S3. Loads in flight during every compute phase but the last. Grid
// 1024 blocks. warm_k deliberately untouched (clean A/B on the
// continuity mechanism; port to warm rescan next round if it wins).
//
// R14 lesson: in-wave burst MLP is NOT the lever (44->51us). Continuity is
// the remaining hypothesis; if R15 doesn't move, ~3 TB/s is a per-CU
// read-path ceiling -> switch to halving bytes (symmetric upper-triangle).
// R13 lesson: ROUNDS must be 12 = ceil(log2(4096)) — harness re-poisons
// inputs for the post-timing check; 10 rounds failed on a fresh instance.
// NEVER lower below 12. done[]-gated rounds cost only launch overhead.
// R12 geometry kept: chunk l = interleaved column set {k*256+l*4+q}; lane
// l reads float4 index k*64+lane — fully-coalesced 1KB wave loads, per-
// chunk min lane-private, ONE wave_min64 per row. cand[] = 64/row.
// R11 lesson: lane-owns-CONTIGUOUS-chunk destroys coalescing. Interleave.
// R10 lesson: do NOT fuse contraction into the scan kernel.
//
// Layout of d_ws:
//   best : 2*4096 u64  @ 0       (65536 B)
//   comp : 2*4096 i32  @ 65536   (32768 B)
//   done : 2     i32   @ 98304   (8 B)
//   cand : 2*4096*64 u64 @ 98312 (4 MiB)   per-(row,lane-chunk) best edge

#define NPTS 4096
#define NCHUNK 64                   // interleaved chunks per row, 1 per lane
#define NBLK 1024                   // warm blocks per problem (4 rows each)
#define COLDBLK 512                 // cold blocks per problem (8 rows each)
#define ROUNDS 12                   // ceil(log2(4096)) — sufficient for ANY
                                    // input. NEVER lower below 12.

typedef unsigned long long u64;
typedef float nfloat4 __attribute__((ext_vector_type(4)));

__device__ __forceinline__ u64 umin64(u64 a, u64 b) { return a < b ? a : b; }

// [ w_bits:32 | min(i,j):12 | max(i,j):12 ] — strict total order, symmetric.
__device__ __forceinline__ u64 pack_edge(float w, int i, int j) {
    unsigned wb = __float_as_uint(w);
    int u = i < j ? i : j;
    int v = i < j ? j : i;
    return ((u64)wb << 24) | ((u64)(unsigned)u << 12) | (u64)(unsigned)v;
}

__device__ __forceinline__ u64 wave_min64(u64 v) {
    #pragma unroll
    for (int off = 32; off; off >>= 1)
        v = umin64(v, __shfl_down(v, (unsigned)off, 64));
    return v;   // valid in lane 0
}

// Cold scan (round 1, comp = identity): persistent 2-row pipelined waves.
// Wave handles rows i0 = rb*4+wave and i1 = i0+2048. Stages of 8 float4
// loads with P/Q ping-pong so loads stay in flight under compute.
// Lane-private chunk min -> cand[row][lane]; one wave_min64 per row.
// One thread also zeroes done[] and out[].
__global__ __launch_bounds__(256) void cold_k(
    const float* __restrict__ D1, const float* __restrict__ D2,
    u64* __restrict__ best, u64* __restrict__ cand,
    int* __restrict__ done, float* __restrict__ out) {
    if (blockIdx.x == 0 && threadIdx.x == 0) {
        done[0] = 0; done[1] = 0; out[0] = 0.f;
    }
    int pb = blockIdx.x >> 9;           // 1024 blocks: 512 per problem
    int rb = blockIdx.x & (COLDBLK - 1);
    const float* __restrict__ D = pb ? D2 : D1;
    u64* __restrict__ bst = best + pb * NPTS;
    u64* __restrict__ cnd = cand + (size_t)pb * NPTS * NCHUNK;

    int wave = threadIdx.x >> 6, lane = threadIdx.x & 63;
    int i0 = rb * 4 + wave;             // [0, 2048)
    int i1 = i0 + 2048;
    const nfloat4* __restrict__ r0 = (const nfloat4*)(D + (size_t)i0 * NPTS);
    const nfloat4* __restrict__ r1 = (const nfloat4*)(D + (size_t)i1 * NPTS);

    nfloat4 P[8], Q[8];
    #pragma unroll
    for (int k = 0; k < 8; ++k) P[k] = r0[k * 64 + lane];        // S0 issue
    #pragma unroll
    for (int k = 0; k < 8; ++k) Q[k] = r0[(k + 8) * 64 + lane];  // S1 issue

    u64 a0 = ~0ull, a1 = ~0ull, a2 = ~0ull, a3 = ~0ull;
    #pragma unroll
    for (int k = 0; k < 8; ++k) {       // compute S0 (waits only on P)
        int j0 = k * 256 + lane * 4;
        if (j0     != i0) a0 = umin64(a0, pack_edge(P[k].x, i0, j0));
        if (j0 + 1 != i0) a1 = umin64(a1, pack_edge(P[k].y, i0, j0 + 1));
        if (j0 + 2 != i0) a2 = umin64(a2, pack_edge(P[k].z, i0, j0 + 2));
        if (j0 + 3 != i0) a3 = umin64(a3, pack_edge(P[k].w, i0, j0 + 3));
    }
    #pragma unroll
    for (int k = 0; k < 8; ++k) P[k] = r1[k * 64 + lane];        // S2 issue
    #pragma unroll
    for (int k = 0; k < 8; ++k) {       // compute S1 (S2 in flight)
        int j0 = (k + 8) * 256 + lane * 4;
        if (j0     != i0) a0 = umin64(a0, pack_edge(Q[k].x, i0, j0));
        if (j0 + 1 != i0) a1 = umin64(a1, pack_edge(Q[k].y, i0, j0 + 1));
        if (j0 + 2 != i0) a2 = umin64(a2, pack_edge(Q[k].z, i0, j0 + 2));
        if (j0 + 3 != i0) a3 = umin64(a3, pack_edge(Q[k].w, i0, j0 + 3));
    }
    #pragma unroll
    for (int k = 0; k < 8; ++k) Q[k] = r1[(k + 8) * 64 + lane];  // S3 issue

    u64 m0 = umin64(umin64(a0, a1), umin64(a2, a3));
    cnd[i0 * NCHUNK + lane] = m0;       // coalesced 512B store
    u64 bv0 = wave_min64(m0);           // LDS pipe; S3 still in flight
    if (lane == 0) bst[i0] = bv0;

    a0 = ~0ull; a1 = ~0ull; a2 = ~0ull; a3 = ~0ull;
    #pragma unroll
    for (int k = 0; k < 8; ++k) {       // compute S2 (S3 in flight)
        int j0 = k * 256 + lane * 4;
        if (j0     != i1) a0 = umin64(a0, pack_edge(P[k].x, i1, j0));
        if (j0 + 1 != i1) a1 = umin64(a1, pack_edge(P[k].y, i1, j0 + 1));
        if (j0 + 2 != i1) a2 = umin64(a2, pack_edge(P[k].z, i1, j0 + 2));
        if (j0 + 3 != i1) a3 = umin64(a3, pack_edge(P[k].w, i1, j0 + 3));
    }
    #pragma unroll
    for (int k = 0; k < 8; ++k) {       // compute S3
        int j0 = (k + 8) * 256 + lane * 4;
        if (j0     != i1) a0 = umin64(a0, pack_edge(Q[k].x, i1, j0));
        if (j0 + 1 != i1) a1 = umin64(a1, pack_edge(Q[k].y, i1, j0 + 1));
        if (j0 + 2 != i1) a2 = umin64(a2, pack_edge(Q[k].z, i1, j0 + 2));
        if (j0 + 3 != i1) a3 = umin64(a3, pack_edge(Q[k].w, i1, j0 + 3));
    }
    u64 m1 = umin64(umin64(a0, a1), umin64(a2, a3));
    cnd[i1 * NCHUNK + lane] = m1;
    u64 bv1 = wave_min64(m1);
    if (lane == 0) bst[i1] = bv1;
}

// Warm scan: 1 row per wave. Each lane validates its own candidate against
// current comp; dead lanes privately rescan their interleaved chunk with
// hoisted loads. One wave_min64 per row; atomicMin per row.
__global__ __launch_bounds__(256) void warm_k(
    const float* __restrict__ D1, const float* __restrict__ D2,
    u64* __restrict__ best, const int* __restrict__ comp,
    const int* __restrict__ done, u64* __restrict__ cand) {
    int pb = blockIdx.x >> 10;
    if (done[pb]) return;
    int rb = blockIdx.x & (NBLK - 1);
    const float* __restrict__ D = pb ? D2 : D1;
    const int* __restrict__ cmpg = comp + pb * NPTS;
    u64* __restrict__ bst = best + pb * NPTS;
    u64* __restrict__ cnd = cand + (size_t)pb * NPTS * NCHUNK;

    int wave = threadIdx.x >> 6, lane = threadIdx.x & 63;
    int i = rb * 4 + wave;
    int ci = cmpg[i];

    u64 live = ~0ull;
    u64 c = cnd[i * NCHUNK + lane];      // coalesced 64-lane load
    if (c != ~0ull) {                    // ~0ull: chunk permanently all-internal
        int u = (int)((c >> 12) & 0xFFF), v = (int)(c & 0xFFF);
        int j = (u == i) ? v : u;
        if (cmpg[j] != ci) {
            live = c;                    // far endpoint still external -> exact
        } else {
            // absorbed -> lane-private rescan of interleaved chunk.
            const nfloat4* __restrict__ row =
                (const nfloat4*)(D + (size_t)i * NPTS);
            nfloat4 w[16];
            #pragma unroll
            for (int k = 0; k < 16; ++k) w[k] = row[k * 64 + lane];
            u64 acc[4] = { ~0ull, ~0ull, ~0ull, ~0ull };
            #pragma unroll
            for (int k = 0; k < 16; ++k) {
                int j0 = k * 256 + lane * 4;
                int4 cj = *(const int4*)&cmpg[j0];   // L1-hot (16 KB array)
                // diagonal j==i auto-excluded: cmpg[i] == ci
                if (cj.x != ci) acc[k & 3] = umin64(acc[k & 3], pack_edge(w[k].x, i, j0));
                if (cj.y != ci) acc[k & 3] = umin64(acc[k & 3], pack_edge(w[k].y, i, j0 + 1));
                if (cj.z != ci) acc[k & 3] = umin64(acc[k & 3], pack_edge(w[k].z, i, j0 + 2));
                if (cj.w != ci) acc[k & 3] = umin64(acc[k & 3], pack_edge(w[k].w, i, j0 + 3));
            }
            u64 m = umin64(umin64(acc[0], acc[1]), umin64(acc[2], acc[3]));
            cnd[i * NCHUNK + lane] = m;
            live = m;
        }
    }
    u64 rmin = wave_min64(live);
    // pre-check: stale plain read >= current (best monotone decreasing) -> safe
    if (lane == 0 && rmin != ~0ull && rmin < bst[ci]) atomicMin(&bst[ci], rmin);
}

// One block (1024 threads) per problem: hook, break 2-cycles, accumulate
// deduped edge losses, pointer-jump, relabel, reset best, set done, add loss.
// identity=1 for round 1 (comp[x]==x implicit -> comp needs no init kernel).
__global__ __launch_bounds__(1024) void contract_k(
    const float* __restrict__ D1, const float* __restrict__ D2,
    u64* __restrict__ best, int* __restrict__ comp,
    int* __restrict__ done, float* __restrict__ out, int identity) {
    int pb = blockIdx.x;
    if (!identity && done[pb]) return;
    u64* __restrict__ bst = best + pb * NPTS;
    int* __restrict__ cmp = comp + pb * NPTS;

    __shared__ int link_s[NPTS];
    __shared__ float red_s[16];
    __shared__ int flag_s;
    int t = threadIdx.x;
    float loss = 0.f;

    int eu[4], ev[4], nl[4];
    bool act[4];

    for (int q = 0; q < 4; ++q) {
        int c = t + q * 1024;
        u64 b = bst[c];
        bool a = (b != ~0ull);
        act[q] = a;
        int u = (int)((b >> 12) & 0xFFF), v = (int)(b & 0xFFF);
        eu[q] = u; ev[q] = v;
        int l = c;
        if (a) {
            if (identity) l = (u == c) ? v : u;
            else { int cu = cmp[u]; l = (cu == c) ? cmp[v] : cu; }
        }
        link_s[c] = l;
    }
    __syncthreads();

    for (int q = 0; q < 4; ++q) {
        int c = t + q * 1024;
        int l = link_s[c];
        bool is2 = (l != c) && (link_s[l] == c);
        if (act[q] && !(is2 && c > l)) {
            size_t off = (size_t)eu[q] * NPTS + ev[q];
            float d = D1[off] - D2[off];
            loss += d * d;
        }
        nl[q] = (is2 && c < l) ? c : l;
    }
    __syncthreads();
    for (int q = 0; q < 4; ++q) link_s[t + q * 1024] = nl[q];
    __syncthreads();

    for (int it = 0; it < 13; ++it) {
        if (t == 0) flag_s = 0;
        __syncthreads();
        bool ch = false;
        for (int q = 0; q < 4; ++q) {
            int c = t + q * 1024;
            int l = link_s[c];
            int ll = link_s[l];
            nl[q] = ll;
            ch |= (ll != l);
        }
        if (ch) flag_s = 1;
        __syncthreads();
        for (int q = 0; q < 4; ++q) link_s[t + q * 1024] = nl[q];
        __syncthreads();
        if (!flag_s) break;
    }

    int c0 = identity ? 0 : cmp[0];
    __syncthreads();
    int root0 = link_s[c0];
    int same = 1;
    for (int q = 0; q < 4; ++q) {
        int v = t + q * 1024;
        int oc = identity ? v : cmp[v];
        int r = link_s[oc];
        cmp[v] = r;
        same &= (r == root0);
        bst[v] = ~0ull;
    }
    int all = __syncthreads_and(same);
    if (all && t == 0) done[pb] = 1;

    #pragma unroll
    for (int off = 32; off; off >>= 1) loss += __shfl_down(loss, (unsigned)off, 64);
    int wave = t >> 6, lane = t & 63;
    if (lane == 0) red_s[wave] = loss;
    __syncthreads();
    if (t == 0) {
        float s = 0.f;
        for (int wv = 0; wv < 16; ++wv) s += red_s[wv];
        atomicAdd(out, s);
    }
}

extern "C" void kernel_launch(void* const* d_in, const int* in_sizes, int n_in,
                              void* d_out, int out_size, void* d_ws, size_t ws_size,
                              hipStream_t stream) {
    const float* D1 = (const float*)d_in[0];   // input_distances  (4096x4096 f32)
    const float* D2 = (const float*)d_in[1];   // latent_distances (4096x4096 f32)
    float* out = (float*)d_out;

    char* ws = (char*)d_ws;
    u64* best = (u64*)ws;                          // 65536 B
    int* comp = (int*)(ws + 65536);                // 32768 B
    int* done = (int*)(ws + 65536 + 32768);        // 8 B
    u64* cand = (u64*)(ws + 98312);                // 4 MiB

    cold_k<<<2 * COLDBLK, 256, 0, stream>>>(D1, D2, best, cand, done, out);
    contract_k<<<2, 1024, 0, stream>>>(D1, D2, best, comp, done, out, 1);
    for (int r = 1; r < ROUNDS; ++r) {
        warm_k<<<2 * NBLK, 256, 0, stream>>>(D1, D2, best, comp, done, cand);
        contract_k<<<2, 1024, 0, stream>>>(D1, D2, best, comp, done, out, 0);
    }
}

// Round 6
// 166.501 us; speedup vs baseline: 1.0817x; 1.0744x over previous
//
#include <hip/hip_runtime.h>
#include <stdint.h>

// TopoAELoss: two dense-graph MSTs (Boruvka) + sum of squared weight
// differences over both MST edge sets.
//
// R16 change: K=2 distinct-component candidate cache. Evidence: R13/R14/
// R15 established that every scan variant at full occupancy consumes
// ~3.0-3.1 TB/s (reads) — the effective read ceiling for this kernel
// family (writes hit 6.7 TB/s, fillBuffer) — so cold_k (R13 form, 44us,
// VGPR 12, max occupancy) is AT its roofline; only byte reduction helps.
// The remaining cost is warm rounds (~75us of 166): the heavy round
// rescans every chunk whose single candidate died (f~0.5 -> 56 MB).
// Now cache rank-1 AND rank-2 per chunk, where rank-2 = min over
// elements with comp != comp(rank-1). Components only grow, so any
// currently-external element was in the rank-2 pool => if rank-1 died
// but rank-2's far comp is still external, rank-2 is EXACTLY the chunk
// min. Rescan only when both die (~f^2). If rank-1 dies and rank-2 is
// the ~0 sentinel (no second distinct comp existed), the chunk is
// permanently internal -> write permanent sentinel. cand2 is read ONLY
// when rank-1 is dead (sparse) so cheap rounds stay cheap. Rescans
// refresh both ranks with CURRENT comps (top-2-distinct-comp streaming).
//
// R15 lesson: scan throughput tracks occupancy only; pipelining/2-row
// persistence regressed (57us @ 25% occ). Keep VGPR minimal, grid maximal.
// R14 lesson: burst load hoisting regressed (51us). Keep rolled loops.
// R13 lesson: ROUNDS must be 12 = ceil(log2(4096)) — harness re-poisons
// inputs for post-timing check. NEVER lower below 12.
// R12 geometry: chunk l = interleaved cols {k*256+l*4+q}; lane l reads
// float4 index k*64+lane (coalesced 1KB wave loads), lane-private min,
// ONE wave_min64 per row.
// R11 lesson: contiguous lane chunks destroy coalescing. Interleave.
// R10 lesson: do NOT fuse contraction into the scan kernel.
//
// Layout of d_ws (~8.5 MiB):
//   best  : 2*4096 u64  @ 0        (65536 B)
//   comp  : 2*4096 i32  @ 65536    (32768 B)
//   done  : 2     i32   @ 98304    (8 B)
//   cand1 : 2*4096*64 u64 @ 98312            (4 MiB)  rank-1 per (row,chunk)
//   cand2 : 2*4096*64 u64 @ 98312+4194304    (4 MiB)  rank-2 (distinct comp)

#define NPTS 4096
#define NCHUNK 64                   // interleaved chunks per row, 1 per lane
#define NBLK 1024                   // blocks per problem (4 rows each)
#define ROUNDS 12                   // ceil(log2(4096)) — sufficient for ANY
                                    // input. NEVER lower below 12.

typedef unsigned long long u64;
typedef float nfloat4 __attribute__((ext_vector_type(4)));

__device__ __forceinline__ u64 umin64(u64 a, u64 b) { return a < b ? a : b; }

// [ w_bits:32 | min(i,j):12 | max(i,j):12 ] — strict total order, symmetric.
__device__ __forceinline__ u64 pack_edge(float w, int i, int j) {
    unsigned wb = __float_as_uint(w);
    int u = i < j ? i : j;
    int v = i < j ? j : i;
    return ((u64)wb << 24) | ((u64)(unsigned)u << 12) | (u64)(unsigned)v;
}

__device__ __forceinline__ u64 wave_min64(u64 v) {
    #pragma unroll
    for (int off = 32; off; off >>= 1)
        v = umin64(v, __shfl_down(v, (unsigned)off, 64));
    return v;   // valid in lane 0
}

// Cold scan (round 1, comp = identity): 1 row per wave; lane l owns the
// interleaved chunk {k*256 + l*4 + q}. Rolled loop (R13 form — minimal
// VGPR, max occupancy). Tracks the two smallest elements per lane (comps
// are identity -> automatically distinct). Lane-private -> cand1/cand2;
// one wave_min64 -> best[i]. One thread zeroes done[] and out[].
__global__ __launch_bounds__(256) void cold_k(
    const float* __restrict__ D1, const float* __restrict__ D2,
    u64* __restrict__ best, u64* __restrict__ cand1, u64* __restrict__ cand2,
    int* __restrict__ done, float* __restrict__ out) {
    if (blockIdx.x == 0 && threadIdx.x == 0) {
        done[0] = 0; done[1] = 0; out[0] = 0.f;
    }
    int pb = blockIdx.x >> 10;
    int rb = blockIdx.x & (NBLK - 1);
    const float* __restrict__ D = pb ? D2 : D1;
    u64* __restrict__ bst = best + pb * NPTS;
    u64* __restrict__ cn1 = cand1 + (size_t)pb * NPTS * NCHUNK;
    u64* __restrict__ cn2 = cand2 + (size_t)pb * NPTS * NCHUNK;

    int wave = threadIdx.x >> 6, lane = threadIdx.x & 63;
    int i = rb * 4 + wave;
    const nfloat4* __restrict__ row = (const nfloat4*)(D + (size_t)i * NPTS);

    u64 m1 = ~0ull, m2 = ~0ull;
    #pragma unroll
    for (int k = 0; k < 16; ++k) {
        nfloat4 w = row[k * 64 + lane];
        int j0 = k * 256 + lane * 4;
        #pragma unroll
        for (int q = 0; q < 4; ++q) {
            if (j0 + q != i) {
                u64 e = pack_edge(w[q], i, j0 + q);
                if (e < m1) { m2 = m1; m1 = e; }
                else if (e < m2) { m2 = e; }
            }
        }
    }
    cn1[i * NCHUNK + lane] = m1;         // coalesced 64-lane stores
    cn2[i * NCHUNK + lane] = m2;
    u64 bv = wave_min64(m1);
    if (lane == 0) bst[i] = bv;          // comp identity: row-private, no atomic
}

// Warm scan: 1 row per wave. Lane validates rank-1; if dead, checks rank-2
// (exact by the monotone-pool argument); only if both dead, rescans its
// interleaved chunk with top-2-distinct-comp streaming and refreshes both
// ranks. If rank-1 dead and rank-2 == ~0, chunk is permanently internal.
// One wave_min64 per row; atomicMin into best[comp(i)].
__global__ __launch_bounds__(256) void warm_k(
    const float* __restrict__ D1, const float* __restrict__ D2,
    u64* __restrict__ best, const int* __restrict__ comp,
    const int* __restrict__ done, u64* __restrict__ cand1,
    u64* __restrict__ cand2) {
    int pb = blockIdx.x >> 10;
    if (done[pb]) return;
    int rb = blockIdx.x & (NBLK - 1);
    const float* __restrict__ D = pb ? D2 : D1;
    const int* __restrict__ cmpg = comp + pb * NPTS;
    u64* __restrict__ bst = best + pb * NPTS;
    u64* __restrict__ cn1 = cand1 + (size_t)pb * NPTS * NCHUNK;
    u64* __restrict__ cn2 = cand2 + (size_t)pb * NPTS * NCHUNK;

    int wave = threadIdx.x >> 6, lane = threadIdx.x & 63;
    int i = rb * 4 + wave;
    int ci = cmpg[i];

    u64 live = ~0ull;
    u64 c1 = cn1[i * NCHUNK + lane];     // coalesced 64-lane load
    if (c1 != ~0ull) {                   // ~0ull: chunk permanently all-internal
        int u1 = (int)((c1 >> 12) & 0xFFF), v1 = (int)(c1 & 0xFFF);
        int j1 = (u1 == i) ? v1 : u1;
        if (cmpg[j1] != ci) {
            live = c1;                   // rank-1 still external -> exact
        } else {
            u64 c2 = cn2[i * NCHUNK + lane];   // sparse: only when rank-1 dead
            bool resc = true;
            if (c2 == ~0ull) {
                // no second distinct comp existed at refresh -> every element
                // had comp(c1)'s comp or was internal; both now internal.
                cn1[i * NCHUNK + lane] = ~0ull;  // permanent sentinel
                resc = false;
            } else {
                int u2 = (int)((c2 >> 12) & 0xFFF), v2 = (int)(c2 & 0xFFF);
                int j2 = (u2 == i) ? v2 : u2;
                if (cmpg[j2] != ci) { live = c2; resc = false; }  // exact
            }
            if (resc) {
                // both ranks dead -> rescan chunk, refresh with CURRENT comps.
                const nfloat4* __restrict__ row =
                    (const nfloat4*)(D + (size_t)i * NPTS);
                u64 m1 = ~0ull, m2 = ~0ull;
                int cm1 = -1;            // comp of current m1
                #pragma unroll 4
                for (int k = 0; k < 16; ++k) {
                    nfloat4 w = row[k * 64 + lane];
                    int j0 = k * 256 + lane * 4;
                    int4 cj = *(const int4*)&cmpg[j0];   // L1-hot (16 KB)
                    // diagonal j==i auto-excluded: cmpg[i] == ci
                    #pragma unroll
                    for (int q = 0; q < 4; ++q) {
                        int cq = (q == 0) ? cj.x : (q == 1) ? cj.y
                               : (q == 2) ? cj.z : cj.w;
                        if (cq != ci) {
                            u64 e = pack_edge(w[q], i, j0 + q);
                            if (e < m1) {
                                if (cq == cm1) { m1 = e; }
                                else { m2 = m1; m1 = e; cm1 = cq; }
                            } else if (e < m2 && cq != cm1) {
                                m2 = e;
                            }
                        }
                    }
                }
                cn1[i * NCHUNK + lane] = m1;   // m1==~0 -> permanent internal
                cn2[i * NCHUNK + lane] = m2;
                live = m1;
            }
        }
    }
    u64 rmin = wave_min64(live);
    // pre-check: stale plain read >= current (best monotone decreasing) -> safe
    if (lane == 0 && rmin != ~0ull && rmin < bst[ci]) atomicMin(&bst[ci], rmin);
}

// One block (1024 threads) per problem: hook, break 2-cycles, accumulate
// deduped edge losses, pointer-jump, relabel, reset best, set done, add loss.
// identity=1 for round 1 (comp[x]==x implicit -> comp needs no init kernel).
__global__ __launch_bounds__(1024) void contract_k(
    const float* __restrict__ D1, const float* __restrict__ D2,
    u64* __restrict__ best, int* __restrict__ comp,
    int* __restrict__ done, float* __restrict__ out, int identity) {
    int pb = blockIdx.x;
    if (!identity && done[pb]) return;
    u64* __restrict__ bst = best + pb * NPTS;
    int* __restrict__ cmp = comp + pb * NPTS;

    __shared__ int link_s[NPTS];
    __shared__ float red_s[16];
    __shared__ int flag_s;
    int t = threadIdx.x;
    float loss = 0.f;

    int eu[4], ev[4], nl[4];
    bool act[4];

    for (int q = 0; q < 4; ++q) {
        int c = t + q * 1024;
        u64 b = bst[c];
        bool a = (b != ~0ull);
        act[q] = a;
        int u = (int)((b >> 12) & 0xFFF), v = (int)(b & 0xFFF);
        eu[q] = u; ev[q] = v;
        int l = c;
        if (a) {
            if (identity) l = (u == c) ? v : u;
            else { int cu = cmp[u]; l = (cu == c) ? cmp[v] : cu; }
        }
        link_s[c] = l;
    }
    __syncthreads();

    for (int q = 0; q < 4; ++q) {
        int c = t + q * 1024;
        int l = link_s[c];
        bool is2 = (l != c) && (link_s[l] == c);
        if (act[q] && !(is2 && c > l)) {
            size_t off = (size_t)eu[q] * NPTS + ev[q];
            float d = D1[off] - D2[off];
            loss += d * d;
        }
        nl[q] = (is2 && c < l) ? c : l;
    }
    __syncthreads();
    for (int q = 0; q < 4; ++q) link_s[t + q * 1024] = nl[q];
    __syncthreads();

    for (int it = 0; it < 13; ++it) {
        if (t == 0) flag_s = 0;
        __syncthreads();
        bool ch = false;
        for (int q = 0; q < 4; ++q) {
            int c = t + q * 1024;
            int l = link_s[c];
            int ll = link_s[l];
            nl[q] = ll;
            ch |= (ll != l);
        }
        if (ch) flag_s = 1;
        __syncthreads();
        for (int q = 0; q < 4; ++q) link_s[t + q * 1024] = nl[q];
        __syncthreads();
        if (!flag_s) break;
    }

    int c0 = identity ? 0 : cmp[0];
    __syncthreads();
    int root0 = link_s[c0];
    int same = 1;
    for (int q = 0; q < 4; ++q) {
        int v = t + q * 1024;
        int oc = identity ? v : cmp[v];
        int r = link_s[oc];
        cmp[v] = r;
        same &= (r == root0);
        bst[v] = ~0ull;
    }
    int all = __syncthreads_and(same);
    if (all && t == 0) done[pb] = 1;

    #pragma unroll
    for (int off = 32; off; off >>= 1) loss += __shfl_down(loss, (unsigned)off, 64);
    int wave = t >> 6, lane = t & 63;
    if (lane == 0) red_s[wave] = loss;
    __syncthreads();
    if (t == 0) {
        float s = 0.f;
        for (int wv = 0; wv < 16; ++wv) s += red_s[wv];
        atomicAdd(out, s);
    }
}

extern "C" void kernel_launch(void* const* d_in, const int* in_sizes, int n_in,
                              void* d_out, int out_size, void* d_ws, size_t ws_size,
                              hipStream_t stream) {
    const float* D1 = (const float*)d_in[0];   // input_distances  (4096x4096 f32)
    const float* D2 = (const float*)d_in[1];   // latent_distances (4096x4096 f32)
    float* out = (float*)d_out;

    char* ws = (char*)d_ws;
    u64* best = (u64*)ws;                          // 65536 B
    int* comp = (int*)(ws + 65536);                // 32768 B
    int* done = (int*)(ws + 65536 + 32768);        // 8 B
    u64* cand1 = (u64*)(ws + 98312);               // 4 MiB
    u64* cand2 = (u64*)(ws + 98312 + 4194304);     // 4 MiB

    cold_k<<<2 * NBLK, 256, 0, stream>>>(D1, D2, best, cand1, cand2, done, out);
    contract_k<<<2, 1024, 0, stream>>>(D1, D2, best, comp, done, out, 1);
    for (int r = 1; r < ROUNDS; ++r) {
        warm_k<<<2 * NBLK, 256, 0, stream>>>(D1, D2, best, comp, done, cand1, cand2);
        contract_k<<<2, 1024, 0, stream>>>(D1, D2, best, comp, done, out, 0);
    }
}

// Round 7
// 136.537 us; speedup vs baseline: 1.3191x; 1.2195x over previous
//
#include <hip/hip_runtime.h>
#include <stdint.h>

// TopoAELoss: two dense-graph MSTs (Boruvka) + sum of squared weight
// differences over both MST edge sets.
//
// R17 change: exploit matrix SYMMETRY in the cold scan. Evidence: all scan
// variants (R10-R15) pin at ~3.1 TB/s read consumption at full occupancy
// (empirical read ceiling; even m13's copy reads at ~3.15), so cold at
// 128 MiB / 45us was AT its roofline — only byte reduction helps. New
// cold = tile_k: 64x64 upper-triangle tiles (r<=c), tile loaded once into
// LDS (pad 65 -> (l+j)%32, 2-way conflict = free); wave0 row-mins ->
// cand[i][c], wave1 col-mins -> cand[j][r] (= row j's chunk-r min by
// symmetry). Halves cold bytes to ~65 MiB. Inner loops are float-argmin
// (3 ops/elem) + one pack_edge at the end (distinct weights assumed, per
// reference). finalize_k reduces cand rows -> best. Chunks are now
// CONTIGUOUS 64 cols; warm rescan is quarter-wave cooperative (4 dead
// chunks per pass, 256B coalesced per quarter, 4-step shfl_down reduce) —
// avoids R11's uncoalesced lane-private trap. R16's rank-2 cache REVERTED
// (null: R13==R16==166.5us; candidate deaths are correlated late).
//
// R15 lesson: scan throughput tracks occupancy; keep VGPR small, grid big.
// R14 lesson: burst load hoisting regressed. Keep rolled loops.
// R13 lesson: ROUNDS must be 12 = ceil(log2(4096)) — harness re-poisons
// inputs for the post-timing check. NEVER lower below 12.
// R11 lesson: per-lane CONTIGUOUS global rescans destroy coalescing; any
// contiguous range must be read wave/quarter-cooperatively.
// R10 lesson: do NOT fuse contraction into the scan kernel.
//
// Layout of d_ws (~4.3 MiB):
//   best : 2*4096 u64  @ 0       (65536 B)
//   comp : 2*4096 i32  @ 65536   (32768 B)
//   done : 2     i32   @ 98304   (8 B)
//   cand : 2*4096*64 u64 @ 98312 (4 MiB)   per-(row,64col-chunk) best edge

#define NPTS 4096
#define NCHUNK 64                   // contiguous 64-col chunks per row
#define NBLK 1024                   // warm blocks per problem (4 rows each)
#define ROUNDS 12                   // ceil(log2(4096)) — sufficient for ANY
                                    // input. NEVER lower below 12.

typedef unsigned long long u64;

__device__ __forceinline__ u64 umin64(u64 a, u64 b) { return a < b ? a : b; }

// [ w_bits:32 | min(i,j):12 | max(i,j):12 ] — strict total order, symmetric.
__device__ __forceinline__ u64 pack_edge(float w, int i, int j) {
    unsigned wb = __float_as_uint(w);
    int u = i < j ? i : j;
    int v = i < j ? j : i;
    return ((u64)wb << 24) | ((u64)(unsigned)u << 12) | (u64)(unsigned)v;
}

__device__ __forceinline__ u64 wave_min64(u64 v) {
    #pragma unroll
    for (int off = 32; off; off >>= 1)
        v = umin64(v, __shfl_down(v, (unsigned)off, 64));
    return v;   // valid in lane 0
}

// Cold tile scan: one block per 64x64 tile (r<=c; lower tiles exit).
// Load tile to LDS (coalesced float4, 4 row-segments of 256B per wave
// instr). wave0: per-row argmin -> cand[R0+l][c]. wave1 (r<c): per-col
// argmin -> cand[C0+l][r] (valid by symmetry). Diagonal tiles exclude
// j==i and skip wave1 (row-min already covers the full chunk).
__global__ __launch_bounds__(256) void tile_k(
    const float* __restrict__ D1, const float* __restrict__ D2,
    u64* __restrict__ cand) {
    int pb = blockIdx.x >> 12;
    int t  = blockIdx.x & 4095;
    int r = t >> 6, c = t & 63;
    if (r > c) return;
    const float* __restrict__ D = pb ? D2 : D1;
    u64* __restrict__ cnd = cand + (size_t)pb * NPTS * NCHUNK;

    __shared__ float ts[64][65];    // pad 65: banks (row+col)%32 -> 2-way, free
    int R0 = r << 6, C0 = c << 6;
    int tid = threadIdx.x;

    #pragma unroll
    for (int e = 0; e < 4; ++e) {
        int idx4 = tid + e * 256;
        int row = idx4 >> 4, c4 = idx4 & 15;
        const float4* __restrict__ rp =
            (const float4*)(D + (size_t)(R0 + row) * NPTS + C0);
        float4 w = rp[c4];
        ts[row][c4 * 4    ] = w.x; ts[row][c4 * 4 + 1] = w.y;
        ts[row][c4 * 4 + 2] = w.z; ts[row][c4 * 4 + 3] = w.w;
    }
    __syncthreads();

    int wave = tid >> 6, lane = tid & 63;
    if (wave == 0) {
        int i = R0 + lane;
        float wm = 3.4e38f; int jm = 0;
        if (r == c) {
            for (int j = 0; j < 64; ++j) {
                float x = ts[lane][j];
                if ((C0 + j) != i && x < wm) { wm = x; jm = C0 + j; }
            }
        } else {
            for (int j = 0; j < 64; ++j) {
                float x = ts[lane][j];
                if (x < wm) { wm = x; jm = C0 + j; }
            }
        }
        cnd[i * NCHUNK + c] = pack_edge(wm, i, jm);
    } else if (wave == 1 && r != c) {
        int jcol = C0 + lane;
        float wm = 3.4e38f; int im = 0;
        for (int k2 = 0; k2 < 64; ++k2) {
            float x = ts[k2][lane];
            if (x < wm) { wm = x; im = R0 + k2; }
        }
        cnd[jcol * NCHUNK + r] = pack_edge(wm, jcol, im);
    }
}

// Reduce cand rows -> best (coalesced 512B read per row, one wave_min64).
// Also zeroes done[] and out[] (read only by later kernels).
__global__ __launch_bounds__(256) void finalize_k(
    u64* __restrict__ best, const u64* __restrict__ cand,
    int* __restrict__ done, float* __restrict__ out) {
    if (blockIdx.x == 0 && threadIdx.x == 0) {
        done[0] = 0; done[1] = 0; out[0] = 0.f;
    }
    int pb = blockIdx.x >> 10;
    int rb = blockIdx.x & (NBLK - 1);
    const u64* __restrict__ cnd = cand + (size_t)pb * NPTS * NCHUNK;
    int wave = threadIdx.x >> 6, lane = threadIdx.x & 63;
    int i = rb * 4 + wave;
    u64 bv = wave_min64(cnd[i * NCHUNK + lane]);
    if (lane == 0) best[pb * NPTS + i] = bv;   // identity comp: row-private
}

// Warm scan: 1 row per wave. Lane l validates cand[i][l] (far endpoint
// still external -> still exact; components only grow). Dead chunks are
// rescanned cooperatively: 4 chunks per pass, one quarter-wave each
// (16 lanes x float4 = 256B coalesced), 4-step shfl reduce, refresh cand.
// ~0ull rescan result = chunk permanently internal. One wave_min64/row.
__global__ __launch_bounds__(256) void warm_k(
    const float* __restrict__ D1, const float* __restrict__ D2,
    u64* __restrict__ best, const int* __restrict__ comp,
    const int* __restrict__ done, u64* __restrict__ cand) {
    int pb = blockIdx.x >> 10;
    if (done[pb]) return;
    int rb = blockIdx.x & (NBLK - 1);
    const float* __restrict__ D = pb ? D2 : D1;
    const int* __restrict__ cmpg = comp + pb * NPTS;
    u64* __restrict__ bst = best + pb * NPTS;
    u64* __restrict__ cnd = cand + (size_t)pb * NPTS * NCHUNK;

    int wave = threadIdx.x >> 6, lane = threadIdx.x & 63;
    int i = rb * 4 + wave;
    int ci = cmpg[i];

    u64 live = ~0ull;
    bool dead = false;
    u64 c = cnd[i * NCHUNK + lane];      // coalesced 64-lane load
    if (c != ~0ull) {                    // ~0ull: chunk permanently all-internal
        int u = (int)((c >> 12) & 0xFFF), v = (int)(c & 0xFFF);
        int j = (u == i) ? v : u;
        if (cmpg[j] != ci) live = c;     // still external -> still exact
        else dead = true;
    }

    u64 extra = ~0ull;
    u64 mask = __ballot(dead);           // wave-uniform
    if (mask) {
        const float4* __restrict__ rowf = (const float4*)(D + (size_t)i * NPTS);
        const int4* __restrict__ cmp4 = (const int4*)cmpg;
        int g = lane >> 4, m16 = lane & 15;
        while (mask) {
            int kq = -1;                 // chunk assigned to my quarter
            #pragma unroll
            for (int s = 0; s < 4; ++s) {
                int kk = mask ? (int)(__ffsll((long long)mask) - 1) : -1;
                if (kk >= 0) mask &= mask - 1;
                if (s == g) kq = kk;
            }
            u64 e = ~0ull;
            if (kq >= 0) {
                float4 w = rowf[kq * 16 + m16];      // 256B coalesced/quarter
                int4 cj = cmp4[kq * 16 + m16];       // L1/L2-hot (16 KB)
                int j0 = kq * 64 + m16 * 4;
                // diagonal j==i auto-excluded: cmpg[i] == ci
                if (cj.x != ci) e = umin64(e, pack_edge(w.x, i, j0));
                if (cj.y != ci) e = umin64(e, pack_edge(w.y, i, j0 + 1));
                if (cj.z != ci) e = umin64(e, pack_edge(w.z, i, j0 + 2));
                if (cj.w != ci) e = umin64(e, pack_edge(w.w, i, j0 + 3));
            }
            #pragma unroll
            for (int off = 8; off; off >>= 1)
                e = umin64(e, __shfl_down(e, (unsigned)off, 16));
            if (kq >= 0 && m16 == 0) {
                cnd[i * NCHUNK + kq] = e;            // ~0ull -> permanent
                extra = umin64(extra, e);
            }
        }
    }
    u64 rmin = wave_min64(umin64(live, extra));
    // pre-check: stale plain read >= current (best monotone decreasing) -> safe
    if (lane == 0 && rmin != ~0ull && rmin < bst[ci]) atomicMin(&bst[ci], rmin);
}

// One block (1024 threads) per problem: hook, break 2-cycles, accumulate
// deduped edge losses, pointer-jump, relabel, reset best, set done, add loss.
// identity=1 for round 1 (comp[x]==x implicit -> comp needs no init kernel).
__global__ __launch_bounds__(1024) void contract_k(
    const float* __restrict__ D1, const float* __restrict__ D2,
    u64* __restrict__ best, int* __restrict__ comp,
    int* __restrict__ done, float* __restrict__ out, int identity) {
    int pb = blockIdx.x;
    if (!identity && done[pb]) return;
    u64* __restrict__ bst = best + pb * NPTS;
    int* __restrict__ cmp = comp + pb * NPTS;

    __shared__ int link_s[NPTS];
    __shared__ float red_s[16];
    __shared__ int flag_s;
    int t = threadIdx.x;
    float loss = 0.f;

    int eu[4], ev[4], nl[4];
    bool act[4];

    for (int q = 0; q < 4; ++q) {
        int c = t + q * 1024;
        u64 b = bst[c];
        bool a = (b != ~0ull);
        act[q] = a;
        int u = (int)((b >> 12) & 0xFFF), v = (int)(b & 0xFFF);
        eu[q] = u; ev[q] = v;
        int l = c;
        if (a) {
            if (identity) l = (u == c) ? v : u;
            else { int cu = cmp[u]; l = (cu == c) ? cmp[v] : cu; }
        }
        link_s[c] = l;
    }
    __syncthreads();

    for (int q = 0; q < 4; ++q) {
        int c = t + q * 1024;
        int l = link_s[c];
        bool is2 = (l != c) && (link_s[l] == c);
        if (act[q] && !(is2 && c > l)) {
            size_t off = (size_t)eu[q] * NPTS + ev[q];
            float d = D1[off] - D2[off];
            loss += d * d;
        }
        nl[q] = (is2 && c < l) ? c : l;
    }
    __syncthreads();
    for (int q = 0; q < 4; ++q) link_s[t + q * 1024] = nl[q];
    __syncthreads();

    for (int it = 0; it < 13; ++it) {
        if (t == 0) flag_s = 0;
        __syncthreads();
        bool ch = false;
        for (int q = 0; q < 4; ++q) {
            int c = t + q * 1024;
            int l = link_s[c];
            int ll = link_s[l];
            nl[q] = ll;
            ch |= (ll != l);
        }
        if (ch) flag_s = 1;
        __syncthreads();
        for (int q = 0; q < 4; ++q) link_s[t + q * 1024] = nl[q];
        __syncthreads();
        if (!flag_s) break;
    }

    int c0 = identity ? 0 : cmp[0];
    __syncthreads();
    int root0 = link_s[c0];
    int same = 1;
    for (int q = 0; q < 4; ++q) {
        int v = t + q * 1024;
        int oc = identity ? v : cmp[v];
        int r = link_s[oc];
        cmp[v] = r;
        same &= (r == root0);
        bst[v] = ~0ull;
    }
    int all = __syncthreads_and(same);
    if (all && t == 0) done[pb] = 1;

    #pragma unroll
    for (int off = 32; off; off >>= 1) loss += __shfl_down(loss, (unsigned)off, 64);
    int wave = t >> 6, lane = t & 63;
    if (lane == 0) red_s[wave] = loss;
    __syncthreads();
    if (t == 0) {
        float s = 0.f;
        for (int wv = 0; wv < 16; ++wv) s += red_s[wv];
        atomicAdd(out, s);
    }
}

extern "C" void kernel_launch(void* const* d_in, const int* in_sizes, int n_in,
                              void* d_out, int out_size, void* d_ws, size_t ws_size,
                              hipStream_t stream) {
    const float* D1 = (const float*)d_in[0];   // input_distances  (4096x4096 f32)
    const float* D2 = (const float*)d_in[1];   // latent_distances (4096x4096 f32)
    float* out = (float*)d_out;

    char* ws = (char*)d_ws;
    u64* best = (u64*)ws;                          // 65536 B
    int* comp = (int*)(ws + 65536);                // 32768 B
    int* done = (int*)(ws + 65536 + 32768);        // 8 B
    u64* cand = (u64*)(ws + 98312);                // 4 MiB

    tile_k<<<2 * 4096, 256, 0, stream>>>(D1, D2, cand);
    finalize_k<<<2 * NBLK, 256, 0, stream>>>(best, cand, done, out);
    contract_k<<<2, 1024, 0, stream>>>(D1, D2, best, comp, done, out, 1);
    for (int r = 1; r < ROUNDS; ++r) {
        warm_k<<<2 * NBLK, 256, 0, stream>>>(D1, D2, best, comp, done, cand);
        contract_k<<<2, 1024, 0, stream>>>(D1, D2, best, comp, done, out, 0);
    }
}